// Round 1
// baseline (660.882 us; speedup 1.0000x reference)
//
#include <hip/hip_runtime.h>

// ConvNN: out[b,g,j] = W1[g]·leaky(W0[g]·x[b] + b0[g]) + b1[g]
// B=1024, SIZE=2048, IN_DIM=D1=D2=64, neg_slope=0.2
#define BATCH 1024
#define NGRP  2048
#define DIM   64
#define MT    128      // batch rows per block
#define LDR   68       // DIM + 4-short pad (8 B) -> 2-way LDS aliasing only (free)

typedef __attribute__((ext_vector_type(8)))  short bf16x8;
typedef __attribute__((ext_vector_type(4)))  short short4v;
typedef __attribute__((ext_vector_type(16))) float f32x16;

__device__ __forceinline__ short f2bf(float f) {
    // round-to-nearest-even f32 -> bf16 (inputs are finite random normals)
    union { float f; unsigned u; } v; v.f = f;
    unsigned r = v.u + 0x7fffu + ((v.u >> 16) & 1u);
    return (short)(r >> 16);
}

__global__ __launch_bounds__(256, 2)
void convnn_kernel(const float* __restrict__ x,  const float* __restrict__ W0,
                   const float* __restrict__ b0, const float* __restrict__ W1,
                   const float* __restrict__ b1, float* __restrict__ out) {
    __shared__ short xs[MT][LDR];    // x tile, bf16
    __shared__ short hs[MT][LDR];    // hidden tile, bf16
    __shared__ short w0s[DIM][LDR];  // W0[g] (N x K row-major)
    __shared__ short w1s[DIM][LDR];  // W1[g]
    __shared__ float b0s[DIM], b1s[DIM];

    const int g     = blockIdx.x >> 3;        // 2048 groups
    const int mbase = (blockIdx.x & 7) * MT;  // 8 batch tiles of 128
    const int tid   = threadIdx.x;

    // ---- stage: x tile (128x64 f32), W0[g], W1[g] (64x64) -> bf16 LDS ----
    {
        const float* xp = x + (size_t)mbase * DIM;
        #pragma unroll
        for (int i = 0; i < 8; ++i) {
            int f   = tid + i * 256;     // float4 index 0..2047
            int row = f >> 4;            // 16 float4 per 64-el row
            int c   = (f & 15) * 4;
            float4 v = *(const float4*)(xp + row * DIM + c);
            short4v s = { f2bf(v.x), f2bf(v.y), f2bf(v.z), f2bf(v.w) };
            *(short4v*)&xs[row][c] = s;  // 8 B aligned (136*row + 2c)
        }
        const float* w0p = W0 + (size_t)g * DIM * DIM;
        const float* w1p = W1 + (size_t)g * DIM * DIM;
        #pragma unroll
        for (int i = 0; i < 4; ++i) {
            int f   = tid + i * 256;     // float4 index 0..1023
            int row = f >> 4;
            int c   = (f & 15) * 4;
            float4 v0 = *(const float4*)(w0p + row * DIM + c);
            short4v s0 = { f2bf(v0.x), f2bf(v0.y), f2bf(v0.z), f2bf(v0.w) };
            *(short4v*)&w0s[row][c] = s0;
            float4 v1 = *(const float4*)(w1p + row * DIM + c);
            short4v s1 = { f2bf(v1.x), f2bf(v1.y), f2bf(v1.z), f2bf(v1.w) };
            *(short4v*)&w1s[row][c] = s1;
        }
        if (tid < DIM)          b0s[tid]       = b0[(size_t)g * DIM + tid];
        else if (tid < 2 * DIM) b1s[tid - DIM] = b1[(size_t)g * DIM + tid - DIM];
    }
    __syncthreads();

    const int lane = tid & 63;
    const int wave = tid >> 6;
    const int lm   = lane & 31;        // row (A) / col (B,C) within 32-tile
    const int koff = (lane >> 5) * 8;  // k sub-block per half-wave
    const int mw   = wave * 32;        // wave's 32-row slab within 128 tile

    // ---- layer 0: H = leaky(X @ W0^T + b0), 32x64 per wave ----
    f32x16 acc0, acc1;
    #pragma unroll
    for (int i = 0; i < 16; ++i) { acc0[i] = 0.f; acc1[i] = 0.f; }
    #pragma unroll
    for (int kk = 0; kk < 4; ++kk) {
        int k = kk * 16 + koff;
        bf16x8 a, bA, bB;
        a.lo  = *(const short4v*)&xs[mw + lm][k];
        a.hi  = *(const short4v*)&xs[mw + lm][k + 4];
        bA.lo = *(const short4v*)&w0s[lm][k];
        bA.hi = *(const short4v*)&w0s[lm][k + 4];
        bB.lo = *(const short4v*)&w0s[32 + lm][k];
        bB.hi = *(const short4v*)&w0s[32 + lm][k + 4];
        acc0 = __builtin_amdgcn_mfma_f32_32x32x16_bf16(a, bA, acc0, 0, 0, 0);
        acc1 = __builtin_amdgcn_mfma_f32_32x32x16_bf16(a, bB, acc1, 0, 0, 0);
    }
    // C/D layout: col = lane&31, row = (r&3) + 8*(r>>2) + 4*(lane>>5)
    #pragma unroll
    for (int r = 0; r < 16; ++r) {
        int row = mw + (r & 3) + 8 * (r >> 2) + 4 * (lane >> 5);
        float v0 = acc0[r] + b0s[lm];
        v0 = v0 > 0.f ? v0 : 0.2f * v0;
        hs[row][lm] = f2bf(v0);
        float v1 = acc1[r] + b0s[32 + lm];
        v1 = v1 > 0.f ? v1 : 0.2f * v1;
        hs[row][32 + lm] = f2bf(v1);
    }
    __syncthreads();

    // ---- layer 1: Out = H @ W1^T + b1 ----
    f32x16 c0, c1;
    #pragma unroll
    for (int i = 0; i < 16; ++i) { c0[i] = 0.f; c1[i] = 0.f; }
    #pragma unroll
    for (int kk = 0; kk < 4; ++kk) {
        int k = kk * 16 + koff;
        bf16x8 a, bA, bB;
        a.lo  = *(const short4v*)&hs[mw + lm][k];
        a.hi  = *(const short4v*)&hs[mw + lm][k + 4];
        bA.lo = *(const short4v*)&w1s[lm][k];
        bA.hi = *(const short4v*)&w1s[lm][k + 4];
        bB.lo = *(const short4v*)&w1s[32 + lm][k];
        bB.hi = *(const short4v*)&w1s[32 + lm][k + 4];
        c0 = __builtin_amdgcn_mfma_f32_32x32x16_bf16(a, bA, c0, 0, 0, 0);
        c1 = __builtin_amdgcn_mfma_f32_32x32x16_bf16(a, bB, c1, 0, 0, 0);
    }
    // store: out[b, g, j]; lanes 0..31 -> 128 B contiguous fp32 per row
    #pragma unroll
    for (int r = 0; r < 16; ++r) {
        int row  = (r & 3) + 8 * (r >> 2) + 4 * (lane >> 5);
        size_t b = (size_t)(mbase + mw + row);
        float* o = out + b * ((size_t)NGRP * DIM) + (size_t)g * DIM;
        o[lm]      = c0[r] + b1s[lm];
        o[32 + lm] = c1[r] + b1s[32 + lm];
    }
}

extern "C" void kernel_launch(void* const* d_in, const int* in_sizes, int n_in,
                              void* d_out, int out_size, void* d_ws, size_t ws_size,
                              hipStream_t stream) {
    const float* x  = (const float*)d_in[0];
    const float* W0 = (const float*)d_in[1];
    const float* b0 = (const float*)d_in[2];
    const float* W1 = (const float*)d_in[3];
    const float* b1 = (const float*)d_in[4];
    float* out = (float*)d_out;
    dim3 grid(NGRP * (BATCH / MT));  // 2048 groups x 8 batch tiles = 16384 blocks
    convnn_kernel<<<grid, dim3(256), 0, stream>>>(x, W0, b0, W1, b1, out);
}

// Round 2
// 606.843 us; speedup vs baseline: 1.0890x; 1.0890x over previous
//
#include <hip/hip_runtime.h>

// ConvNN: out[b,g,j] = W1[g]·leaky(W0[g]·x[b] + b0[g]) + b1[g]
// B=1024, SIZE=2048, IN_DIM=D1=D2=64, neg_slope=0.2
//
// Round-2 structure: one block per group, weights in register fragments
// (loaded once), x pre-converted to bf16 in d_ws by a tiny pre-kernel,
// zero __syncthreads (all data flow is wave-local), paired-column B-frags
// so hs writes are b32 and global stores are dwordx2.
#define BATCH 1024
#define NGRP  2048
#define DIM   64
#define NEG   0.2f
#define OUTSTRIDE ((size_t)NGRP * DIM)   // 131072 floats between batch rows

typedef __attribute__((ext_vector_type(8)))  short bf16x8;
typedef __attribute__((ext_vector_type(4)))  short short4v;
typedef __attribute__((ext_vector_type(16))) float f32x16;

union frag_u { bf16x8 v; unsigned u[4]; short4v h[2]; };

// pack two f32 -> two bf16 (RNE) in one u32 via v_perm
__device__ __forceinline__ unsigned pk_rne(float a, float b) {
    unsigned ua = __float_as_uint(a), ub = __float_as_uint(b);
    ua += 0x7fffu + ((ua >> 16) & 1u);
    ub += 0x7fffu + ((ub >> 16) & 1u);
    // result: low16 = bf16(a), high16 = bf16(b)
    return __builtin_amdgcn_perm(ub, ua, 0x07060302);
}

// ---- pre-kernel: x f32[1024][64] -> bf16[1024][64] in workspace ----
__global__ void cvt_x_kernel(const float4* __restrict__ x, uint2* __restrict__ xb) {
    int i = blockIdx.x * blockDim.x + threadIdx.x;   // 16384 threads, 1 float4 each
    float4 v = x[i];
    uint2 o;
    o.x = pk_rne(v.x, v.y);
    o.y = pk_rne(v.z, v.w);
    xb[i] = o;
}

__global__ __launch_bounds__(256, 3)
void convnn_kernel(const unsigned short* __restrict__ xb,  // bf16 [1024][64]
                   const float* __restrict__ W0, const float* __restrict__ b0,
                   const float* __restrict__ W1, const float* __restrict__ b1,
                   float* __restrict__ out) {
    // per-wave hidden slab: 32 rows x 64 cols bf16, +4 shorts pad
    __shared__ short hs[4][32][68];

    const int g    = blockIdx.x;            // one block per group
    const int tid  = threadIdx.x;
    const int lane = tid & 63;
    const int wave = tid >> 6;
    const int n    = lane & 31;             // fragment row/col index
    const int koff = (lane >> 5) * 8;       // k sub-chunk per half-wave

    // ---- load weight B-fragments once (f32 global -> bf16 regs, RNE) ----
    // paired-column assignment: lane n covers weight rows 2n (even acc) and
    // 2n+1 (odd acc), so accE/accO hold adjacent output columns.
    frag_u w0f[4][2], w1f[4][2];
    {
        const float* w0p = W0 + (size_t)g * DIM * DIM;
        const float* w1p = W1 + (size_t)g * DIM * DIM;
        #pragma unroll
        for (int kk = 0; kk < 4; ++kk) {
            #pragma unroll
            for (int p = 0; p < 2; ++p) {
                const float* r0 = w0p + (size_t)(2 * n + p) * DIM + kk * 16 + koff;
                float4 lo = *(const float4*)r0;
                float4 hi = *(const float4*)(r0 + 4);
                w0f[kk][p].u[0] = pk_rne(lo.x, lo.y);
                w0f[kk][p].u[1] = pk_rne(lo.z, lo.w);
                w0f[kk][p].u[2] = pk_rne(hi.x, hi.y);
                w0f[kk][p].u[3] = pk_rne(hi.z, hi.w);
                const float* r1 = w1p + (size_t)(2 * n + p) * DIM + kk * 16 + koff;
                float4 lo1 = *(const float4*)r1;
                float4 hi1 = *(const float4*)(r1 + 4);
                w1f[kk][p].u[0] = pk_rne(lo1.x, lo1.y);
                w1f[kk][p].u[1] = pk_rne(lo1.z, lo1.w);
                w1f[kk][p].u[2] = pk_rne(hi1.x, hi1.y);
                w1f[kk][p].u[3] = pk_rne(hi1.z, hi1.w);
            }
        }
    }
    const float2 b0v = *(const float2*)(b0 + (size_t)g * DIM + 2 * n);
    const float2 b1v = *(const float2*)(b1 + (size_t)g * DIM + 2 * n);

    short (*h)[68] = hs[wave];

    // prefetch tile 0 A-frags (bf16 direct from global, 16B each)
    bf16x8 a[4];
    {
        int tb = wave * 32;                 // tile t = 0*4 + wave
        const unsigned short* xr = xb + (size_t)(tb + n) * DIM + koff;
        #pragma unroll
        for (int kk = 0; kk < 4; ++kk) a[kk] = *(const bf16x8*)(xr + kk * 16);
    }

    for (int i = 0; i < 8; ++i) {
        const int tb = (i * 4 + wave) * 32; // this wave's 32 batch rows
        // prefetch next tile
        bf16x8 an[4];
        {
            int tn = ((i < 7 ? i + 1 : 7) * 4 + wave) * 32;
            const unsigned short* xr = xb + (size_t)(tn + n) * DIM + koff;
            #pragma unroll
            for (int kk = 0; kk < 4; ++kk) an[kk] = *(const bf16x8*)(xr + kk * 16);
        }

        // ---- layer 0: 32x64 slab, even/odd output columns ----
        f32x16 aE, aO;
        #pragma unroll
        for (int r = 0; r < 16; ++r) { aE[r] = 0.f; aO[r] = 0.f; }
        #pragma unroll
        for (int kk = 0; kk < 4; ++kk) {
            aE = __builtin_amdgcn_mfma_f32_32x32x16_bf16(a[kk], w0f[kk][0].v, aE, 0, 0, 0);
            aO = __builtin_amdgcn_mfma_f32_32x32x16_bf16(a[kk], w0f[kk][1].v, aO, 0, 0, 0);
        }
        // epilogue: bias + leaky + pack pair -> hs (wave-local, no barrier)
        #pragma unroll
        for (int r = 0; r < 16; ++r) {
            int m = (r & 3) + 8 * (r >> 2) + 4 * (lane >> 5);
            float vE = aE[r] + b0v.x; vE = vE > 0.f ? vE : NEG * vE;
            float vO = aO[r] + b0v.y; vO = vO > 0.f ? vO : NEG * vO;
            *(unsigned*)&h[m][2 * n] = pk_rne(vE, vO);
        }

        // ---- layer 1: A-frags from hs (row = n, same-wave data) ----
        f32x16 cE, cO;
        #pragma unroll
        for (int r = 0; r < 16; ++r) { cE[r] = 0.f; cO[r] = 0.f; }
        #pragma unroll
        for (int kk = 0; kk < 4; ++kk) {
            frag_u hf;
            hf.h[0] = *(const short4v*)&h[n][kk * 16 + koff];
            hf.h[1] = *(const short4v*)&h[n][kk * 16 + koff + 4];
            cE = __builtin_amdgcn_mfma_f32_32x32x16_bf16(hf.v, w1f[kk][0].v, cE, 0, 0, 0);
            cO = __builtin_amdgcn_mfma_f32_32x32x16_bf16(hf.v, w1f[kk][1].v, cO, 0, 0, 0);
        }

        // ---- store: lane n writes adjacent cols (2n, 2n+1) -> dwordx2 ----
        float* ob = out + (size_t)tb * OUTSTRIDE + (size_t)g * DIM + 2 * n;
        #pragma unroll
        for (int r = 0; r < 16; ++r) {
            int m = (r & 3) + 8 * (r >> 2) + 4 * (lane >> 5);
            float2 o2;
            o2.x = cE[r] + b1v.x;
            o2.y = cO[r] + b1v.y;
            *(float2*)(ob + (size_t)m * OUTSTRIDE) = o2;
        }

        #pragma unroll
        for (int kk = 0; kk < 4; ++kk) a[kk] = an[kk];
    }
}

extern "C" void kernel_launch(void* const* d_in, const int* in_sizes, int n_in,
                              void* d_out, int out_size, void* d_ws, size_t ws_size,
                              hipStream_t stream) {
    const float* x  = (const float*)d_in[0];
    const float* W0 = (const float*)d_in[1];
    const float* b0 = (const float*)d_in[2];
    const float* W1 = (const float*)d_in[3];
    const float* b1 = (const float*)d_in[4];
    float* out = (float*)d_out;
    unsigned short* xb = (unsigned short*)d_ws;   // bf16 x, 128 KiB

    cvt_x_kernel<<<dim3(64), dim3(256), 0, stream>>>((const float4*)x, (uint2*)xb);
    convnn_kernel<<<dim3(NGRP), dim3(256), 0, stream>>>(xb, W0, b0, W1, b1, out);
}